// Round 4
// baseline (15429.707 us; speedup 1.0000x reference)
//
#include <hip/hip_runtime.h>
#include <math.h>

#define S_ 48
#define B_ 64
#define D_ 300
#define HE_ 300
#define HD_ 256
#define E_ 50
#define A_ 128
#define T_ 50
#define N_ (S_*B_)   // 3072

__device__ __forceinline__ float sigm(float x){ return 1.0f/(1.0f + expf(-x)); }

// ---------------------------------------------------------------------------
// Generic GEMM: C(M,N) = A(M,K) @ W(N,K)^T + bias(N)   (proven)
// MODE 0: store C row-major
// MODE 1: v = tanh(acc+bias); cols [0,256) -> C[m*256+n], [256,512) -> C2
// ---------------------------------------------------------------------------
template<int MODE>
__global__ __launch_bounds__(256)
void gemm_bias_kernel(const float* __restrict__ A, const float* __restrict__ W,
                      const float* __restrict__ bias, float* __restrict__ C,
                      float* __restrict__ C2, int M, int N, int K)
{
  __shared__ float As[16][64];
  __shared__ float Ws[16][64];
  const int tid = threadIdx.x;
  const int bm = blockIdx.y * 64;
  const int bn = blockIdx.x * 64;
  const int tx = tid & 15, ty = tid >> 4;
  const int lr = tid >> 2;
  const int lk = (tid & 3) << 2;
  float acc[4][4] = {{0.f}};
  for (int kb = 0; kb < K; kb += 16) {
    {
      const int row = bm + lr;
      const int k = kb + lk;
      const float* ap = A + (size_t)row * K + k;
      float4 v = make_float4(0.f,0.f,0.f,0.f);
      if (k + 3 < K) v = *reinterpret_cast<const float4*>(ap);
      else {
        if (k   < K) v.x = ap[0];
        if (k+1 < K) v.y = ap[1];
        if (k+2 < K) v.z = ap[2];
        if (k+3 < K) v.w = ap[3];
      }
      As[lk][lr]=v.x; As[lk+1][lr]=v.y; As[lk+2][lr]=v.z; As[lk+3][lr]=v.w;
    }
    {
      const int col = bn + lr;
      const int k = kb + lk;
      float4 v = make_float4(0.f,0.f,0.f,0.f);
      if (col < N) {
        const float* wp = W + (size_t)col * K + k;
        if (k + 3 < K) v = *reinterpret_cast<const float4*>(wp);
        else {
          if (k   < K) v.x = wp[0];
          if (k+1 < K) v.y = wp[1];
          if (k+2 < K) v.z = wp[2];
          if (k+3 < K) v.w = wp[3];
        }
      }
      Ws[lk][lr]=v.x; Ws[lk+1][lr]=v.y; Ws[lk+2][lr]=v.z; Ws[lk+3][lr]=v.w;
    }
    __syncthreads();
    #pragma unroll
    for (int kk = 0; kk < 16; ++kk) {
      float4 a4 = *reinterpret_cast<const float4*>(&As[kk][ty<<2]);
      float4 w4 = *reinterpret_cast<const float4*>(&Ws[kk][tx<<2]);
      const float* a = reinterpret_cast<const float*>(&a4);
      const float* w = reinterpret_cast<const float*>(&w4);
      #pragma unroll
      for (int i = 0; i < 4; ++i)
        #pragma unroll
        for (int j = 0; j < 4; ++j)
          acc[i][j] = fmaf(a[i], w[j], acc[i][j]);
    }
    __syncthreads();
  }
  #pragma unroll
  for (int i = 0; i < 4; ++i) {
    const int m = bm + (ty<<2) + i;
    #pragma unroll
    for (int j = 0; j < 4; ++j) {
      const int n = bn + (tx<<2) + j;
      if (n < N) {
        float v = acc[i][j] + bias[n];
        if (MODE == 0) {
          C[(size_t)m*N + n] = v;
        } else {
          v = tanhf(v);
          if (n < HD_) C[(size_t)m*HD_ + n] = v;
          else         C2[(size_t)m*HD_ + (n-HD_)] = v;
        }
      }
    }
  }
}

// ---------------------------------------------------------------------------
// Encoder recurrent step. Grid (19 colblocks, 4 rowblocks, 2 dirs) = 152 blocks.
// Each block: 16 cols x 16 rows, K=300. Same math order as before (ascending k
// per output) -> bitwise identical results.
// ---------------------------------------------------------------------------
__global__ __launch_bounds__(256)
void enc_step_kernel(const float* __restrict__ gi_f, const float* __restrict__ gi_b,
                     const float* __restrict__ Whh_f, const float* __restrict__ Whh_b,
                     const float* __restrict__ bhh_f, const float* __restrict__ bhh_b,
                     const float* __restrict__ hin_f, float* __restrict__ hout_f,
                     const float* __restrict__ hin_b, float* __restrict__ hout_b,
                     float* __restrict__ out, int t, int layer)
{
  const int dir = blockIdx.z;
  const float* gi  = dir ? gi_b  : gi_f;
  const float* W   = dir ? Whh_b : Whh_f;
  const float* bhh = dir ? bhh_b : bhh_f;
  const float* hin = dir ? hin_b : hin_f;
  float* hout = dir ? hout_b : hout_f;
  const int tt = dir ? (S_-1 - t) : t;

  __shared__ float As[32][17];
  __shared__ float Ws[3][16][36];
  const int tid = threadIdx.x;
  const int bn = blockIdx.x * 16;
  const int rb = blockIdx.y * 16;
  const int tcol = tid & 15;
  const int trow = tid >> 4;     // 0..15
  float accr=0.f, accz=0.f, accn=0.f;

  for (int kb = 0; kb < HE_; kb += 32) {
    __syncthreads();
    if (tid < 128) {
      int row = tid >> 3;          // 0..15
      int k = (tid & 7) << 2;      // 0..28
      const float* ap = hin + (size_t)(rb+row)*HE_ + kb + k;
      float4 v = make_float4(0.f,0.f,0.f,0.f);
      if (kb + k + 3 < HE_) v = *reinterpret_cast<const float4*>(ap);
      else {
        if (kb+k   < HE_) v.x = ap[0];
        if (kb+k+1 < HE_) v.y = ap[1];
        if (kb+k+2 < HE_) v.z = ap[2];
        if (kb+k+3 < HE_) v.w = ap[3];
      }
      As[k][row]=v.x; As[k+1][row]=v.y; As[k+2][row]=v.z; As[k+3][row]=v.w;
    }
    #pragma unroll
    for (int j = 0; j < 6; ++j) {
      int i = tid + j*256;
      int g = i >> 9;
      int cc = (i >> 5) & 15;
      int k = i & 31;
      float v = 0.0f;
      if (bn + cc < HE_ && kb + k < HE_) v = W[(size_t)(g*HE_ + bn + cc)*HE_ + kb + k];
      Ws[g][cc][k] = v;
    }
    __syncthreads();
    #pragma unroll
    for (int kk = 0; kk < 32; kk += 4) {
      float4 wr4 = *reinterpret_cast<const float4*>(&Ws[0][tcol][kk]);
      float4 wz4 = *reinterpret_cast<const float4*>(&Ws[1][tcol][kk]);
      float4 wn4 = *reinterpret_cast<const float4*>(&Ws[2][tcol][kk]);
      const float* wr = reinterpret_cast<const float*>(&wr4);
      const float* wz = reinterpret_cast<const float*>(&wz4);
      const float* wn = reinterpret_cast<const float*>(&wn4);
      #pragma unroll
      for (int u = 0; u < 4; ++u) {
        float a = As[kk+u][trow];
        accr = fmaf(a, wr[u], accr);
        accz = fmaf(a, wz[u], accz);
        accn = fmaf(a, wn[u], accn);
      }
    }
  }
  const int jcol = bn + tcol;
  const int row = rb + trow;
  if (jcol < HE_) {
    const size_t gbase = (size_t)(tt*B_ + row) * (3*HE_);
    float gr = gi[gbase + jcol];
    float gz = gi[gbase + HE_ + jcol];
    float gn = gi[gbase + 2*HE_ + jcol];
    float r = sigm(gr + accr + bhh[jcol]);
    float z = sigm(gz + accz + bhh[HE_ + jcol]);
    float n = tanhf(gn + r*(accn + bhh[2*HE_ + jcol]));
    float ho = hin[(size_t)row*HE_ + jcol];
    float hn = (1.0f - z)*n + z*ho;
    hout[(size_t)row*HE_ + jcol] = hn;
    if (layer == 0) out[(size_t)(tt*B_ + row)*(2*HE_) + dir*HE_ + jcol] = hn;
    else            out[(size_t)(tt*B_ + row)*HE_ + jcol] += hn;
  }
}

// ---------------------------------------------------------------------------
// Pack weights into k-quad float4 layout: P[k4][gc] = W[gc][4*k4 .. 4*k4+3]
// (zero-padded past NK). W is (NC, NK) row-major.
// ---------------------------------------------------------------------------
__global__ __launch_bounds__(256)
void pack4_kernel(const float* __restrict__ W, float4* __restrict__ P,
                  int NC, int NK, int K4)
{
  int idx = blockIdx.x * 256 + threadIdx.x;
  if (idx >= NC * K4) return;
  int k4 = idx / NC, gc = idx % NC;
  int k = k4 << 2;
  const float* wp = W + (size_t)gc * NK + k;
  float4 v = make_float4(0.f,0.f,0.f,0.f);
  if (k   < NK) v.x = wp[0];
  if (k+1 < NK) v.y = wp[1];
  if (k+2 < NK) v.z = wp[2];
  if (k+3 < NK) v.w = wp[3];
  P[(size_t)k4 * NC + gc] = v;
}

// ---------------------------------------------------------------------------
// Persistent decoder, zero cross-block deps. 256 blocks x 1024 threads
// (16 waves/CU). Block owns 12 rows; h0/h1/e in LDS; float4-packed weights
// streamed from L2 (3 loads per 36 FMAs). Thread: c = tid&255, q = tid>>8,
// rows q*3..q*3+2.
// ---------------------------------------------------------------------------
__global__ __launch_bounds__(1024, 4)
void dec_persistent(const float4* __restrict__ Wih0P,  // [13][768]
                    const float4* __restrict__ Whh0P,  // [64][768]
                    const float4* __restrict__ Wih1P,  // [64][768]
                    const float4* __restrict__ Whh1P,  // [64][768]
                    const float4* __restrict__ WoP,    // [64][128]
                    const float* __restrict__ bih0, const float* __restrict__ bhh0,
                    const float* __restrict__ bih1, const float* __restrict__ bhh1,
                    const float* __restrict__ bout,
                    const float* __restrict__ emb,
                    const float* __restrict__ h0init, const float* __restrict__ h1init,
                    float* __restrict__ Y)
{
  __shared__ float h0s[12][256];
  __shared__ float h1s[12][256];
  __shared__ float es[12][52];
  const int tid = threadIdx.x;
  const int R0 = blockIdx.x * 12;
  const int c = tid & 255;
  const int q = tid >> 8;      // 0..3
  const int r0 = q * 3;
  const int lane = tid & 63;

  for (int i = tid; i < 12*64; i += 1024) {
    int r = i >> 6, k = (i & 63) << 2;
    *reinterpret_cast<float4*>(&h0s[r][k]) =
        *reinterpret_cast<const float4*>(&h0init[(size_t)(R0+r)*HD_ + k]);
    *reinterpret_cast<float4*>(&h1s[r][k]) =
        *reinterpret_cast<const float4*>(&h1init[(size_t)(R0+r)*HD_ + k]);
  }
  for (int i = tid; i < 12*52; i += 1024) {
    int r = i / 52, k = i % 52;
    es[r][k] = (k < E_) ? emb[E_ + k] : 0.0f;   // emb[SOS=1], zero pad
  }
  const float b0r = bih0[c] + bhh0[c];
  const float b0z = bih0[HD_+c] + bhh0[HD_+c];
  const float b0ni = bih0[2*HD_+c];
  const float b0nh = bhh0[2*HD_+c];
  const float b1r = bih1[c] + bhh1[c];
  const float b1z = bih1[HD_+c] + bhh1[HD_+c];
  const float b1ni = bih1[2*HD_+c];
  const float b1nh = bhh1[2*HD_+c];
  const float bo0 = bout[lane];
  const float bo1 = bout[64 + lane];
  __syncthreads();

  for (int s = 0; s < T_-1; ++s) {
    // ================= cell 0: x = es (K=52 padded), h = h0s (K=256) =======
    float ar[3]={0,0,0}, az[3]={0,0,0}, ani[3]={0,0,0}, anh[3]={0,0,0};
    for (int k4 = 0; k4 < 13; ++k4) {
      float4 wr = Wih0P[k4*768 + c];
      float4 wz = Wih0P[k4*768 + 256 + c];
      float4 wn = Wih0P[k4*768 + 512 + c];
      #pragma unroll
      for (int r = 0; r < 3; ++r) {
        float4 x = *reinterpret_cast<const float4*>(&es[r0+r][k4<<2]);
        ar[r]=fmaf(x.x,wr.x,ar[r]); ar[r]=fmaf(x.y,wr.y,ar[r]);
        ar[r]=fmaf(x.z,wr.z,ar[r]); ar[r]=fmaf(x.w,wr.w,ar[r]);
        az[r]=fmaf(x.x,wz.x,az[r]); az[r]=fmaf(x.y,wz.y,az[r]);
        az[r]=fmaf(x.z,wz.z,az[r]); az[r]=fmaf(x.w,wz.w,az[r]);
        ani[r]=fmaf(x.x,wn.x,ani[r]); ani[r]=fmaf(x.y,wn.y,ani[r]);
        ani[r]=fmaf(x.z,wn.z,ani[r]); ani[r]=fmaf(x.w,wn.w,ani[r]);
      }
    }
    for (int k4 = 0; k4 < 64; ++k4) {
      float4 wr = Whh0P[k4*768 + c];
      float4 wz = Whh0P[k4*768 + 256 + c];
      float4 wn = Whh0P[k4*768 + 512 + c];
      #pragma unroll
      for (int r = 0; r < 3; ++r) {
        float4 x = *reinterpret_cast<const float4*>(&h0s[r0+r][k4<<2]);
        ar[r]=fmaf(x.x,wr.x,ar[r]); ar[r]=fmaf(x.y,wr.y,ar[r]);
        ar[r]=fmaf(x.z,wr.z,ar[r]); ar[r]=fmaf(x.w,wr.w,ar[r]);
        az[r]=fmaf(x.x,wz.x,az[r]); az[r]=fmaf(x.y,wz.y,az[r]);
        az[r]=fmaf(x.z,wz.z,az[r]); az[r]=fmaf(x.w,wz.w,az[r]);
        anh[r]=fmaf(x.x,wn.x,anh[r]); anh[r]=fmaf(x.y,wn.y,anh[r]);
        anh[r]=fmaf(x.z,wn.z,anh[r]); anh[r]=fmaf(x.w,wn.w,anh[r]);
      }
    }
    __syncthreads();   // all k-loop reads of h0s/es complete
    {
      float hnew[3];
      #pragma unroll
      for (int r = 0; r < 3; ++r) {
        float rg = sigm(ar[r] + b0r);
        float zg = sigm(az[r] + b0z);
        float ng = tanhf(ani[r] + b0ni + rg*(anh[r] + b0nh));
        float hold = h0s[r0+r][c];   // own cell: no cross-thread hazard
        hnew[r] = (1.0f - zg)*ng + zg*hold;
      }
      #pragma unroll
      for (int r = 0; r < 3; ++r) h0s[r0+r][c] = hnew[r];
    }
    __syncthreads();
    // ================= cell 1: x = h0s (K=256), h = h1s (K=256) ============
    #pragma unroll
    for (int r = 0; r < 3; ++r) { ar[r]=0.f; az[r]=0.f; ani[r]=0.f; anh[r]=0.f; }
    for (int k4 = 0; k4 < 64; ++k4) {
      float4 wr = Wih1P[k4*768 + c];
      float4 wz = Wih1P[k4*768 + 256 + c];
      float4 wn = Wih1P[k4*768 + 512 + c];
      #pragma unroll
      for (int r = 0; r < 3; ++r) {
        float4 x = *reinterpret_cast<const float4*>(&h0s[r0+r][k4<<2]);
        ar[r]=fmaf(x.x,wr.x,ar[r]); ar[r]=fmaf(x.y,wr.y,ar[r]);
        ar[r]=fmaf(x.z,wr.z,ar[r]); ar[r]=fmaf(x.w,wr.w,ar[r]);
        az[r]=fmaf(x.x,wz.x,az[r]); az[r]=fmaf(x.y,wz.y,az[r]);
        az[r]=fmaf(x.z,wz.z,az[r]); az[r]=fmaf(x.w,wz.w,az[r]);
        ani[r]=fmaf(x.x,wn.x,ani[r]); ani[r]=fmaf(x.y,wn.y,ani[r]);
        ani[r]=fmaf(x.z,wn.z,ani[r]); ani[r]=fmaf(x.w,wn.w,ani[r]);
      }
    }
    for (int k4 = 0; k4 < 64; ++k4) {
      float4 wr = Whh1P[k4*768 + c];
      float4 wz = Whh1P[k4*768 + 256 + c];
      float4 wn = Whh1P[k4*768 + 512 + c];
      #pragma unroll
      for (int r = 0; r < 3; ++r) {
        float4 x = *reinterpret_cast<const float4*>(&h1s[r0+r][k4<<2]);
        ar[r]=fmaf(x.x,wr.x,ar[r]); ar[r]=fmaf(x.y,wr.y,ar[r]);
        ar[r]=fmaf(x.z,wr.z,ar[r]); ar[r]=fmaf(x.w,wr.w,ar[r]);
        az[r]=fmaf(x.x,wz.x,az[r]); az[r]=fmaf(x.y,wz.y,az[r]);
        az[r]=fmaf(x.z,wz.z,az[r]); az[r]=fmaf(x.w,wz.w,az[r]);
        anh[r]=fmaf(x.x,wn.x,anh[r]); anh[r]=fmaf(x.y,wn.y,anh[r]);
        anh[r]=fmaf(x.z,wn.z,anh[r]); anh[r]=fmaf(x.w,wn.w,anh[r]);
      }
    }
    __syncthreads();
    {
      float hnew[3];
      #pragma unroll
      for (int r = 0; r < 3; ++r) {
        float rg = sigm(ar[r] + b1r);
        float zg = sigm(az[r] + b1z);
        float ng = tanhf(ani[r] + b1ni + rg*(anh[r] + b1nh));
        float hold = h1s[r0+r][c];
        hnew[r] = (1.0f - zg)*ng + zg*hold;
      }
      #pragma unroll
      for (int r = 0; r < 3; ++r) h1s[r0+r][c] = hnew[r];
    }
    __syncthreads();
    // ======== logits + log_softmax + argmax + emb feedback (1 row/wave) ====
    {
      const int w = tid >> 6;
      if (w < 12) {
        const int row = w;
        float a0 = 0.f, a1 = 0.f;
        for (int k4 = 0; k4 < 64; ++k4) {
          float4 w0 = WoP[k4*128 + lane];
          float4 w1 = WoP[k4*128 + 64 + lane];
          float4 h = *reinterpret_cast<const float4*>(&h1s[row][k4<<2]);
          a0 = fmaf(h.x,w0.x,a0); a0 = fmaf(h.y,w0.y,a0);
          a0 = fmaf(h.z,w0.z,a0); a0 = fmaf(h.w,w0.w,a0);
          a1 = fmaf(h.x,w1.x,a1); a1 = fmaf(h.y,w1.y,a1);
          a1 = fmaf(h.z,w1.z,a1); a1 = fmaf(h.w,w1.w,a1);
        }
        float v0 = a0 + bo0;
        float v1 = a1 + bo1;
        float mx = fmaxf(v0, v1);
        #pragma unroll
        for (int off = 32; off >= 1; off >>= 1) mx = fmaxf(mx, __shfl_xor(mx, off));
        float sum = expf(v0 - mx) + expf(v1 - mx);
        #pragma unroll
        for (int off = 32; off >= 1; off >>= 1) sum += __shfl_xor(sum, off);
        float lz = mx + logf(sum);
        float* Yr = Y + ((size_t)s*N_ + R0 + row)*A_;
        Yr[lane]      = v0 - lz;
        Yr[64 + lane] = v1 - lz;
        float bv; int bi;
        if (v0 >= v1) { bv = v0; bi = lane; } else { bv = v1; bi = 64 + lane; }
        #pragma unroll
        for (int off = 32; off >= 1; off >>= 1) {
          float ov = __shfl_xor(bv, off);
          int   oi = __shfl_xor(bi, off);
          if (ov > bv || (ov == bv && oi < bi)) { bv = ov; bi = oi; }
        }
        if (lane < E_) es[row][lane] = emb[(size_t)bi*E_ + lane];
      }
    }
    __syncthreads();   // es ready for next step
  }
}

// ---------------------------------------------------------------------------
extern "C" void kernel_launch(void* const* d_in, const int* in_sizes, int n_in,
                              void* d_out, int out_size, void* d_ws, size_t ws_size,
                              hipStream_t stream)
{
  (void)in_sizes; (void)n_in; (void)out_size; (void)ws_size;
  const float* wv      = (const float*)d_in[0];
  const float* e0f_Wih = (const float*)d_in[1];
  const float* e0f_Whh = (const float*)d_in[2];
  const float* e0f_bih = (const float*)d_in[3];
  const float* e0f_bhh = (const float*)d_in[4];
  const float* e0b_Wih = (const float*)d_in[5];
  const float* e0b_Whh = (const float*)d_in[6];
  const float* e0b_bih = (const float*)d_in[7];
  const float* e0b_bhh = (const float*)d_in[8];
  const float* e1f_Wih = (const float*)d_in[9];
  const float* e1f_Whh = (const float*)d_in[10];
  const float* e1f_bih = (const float*)d_in[11];
  const float* e1f_bhh = (const float*)d_in[12];
  const float* e1b_Wih = (const float*)d_in[13];
  const float* e1b_Whh = (const float*)d_in[14];
  const float* e1b_bih = (const float*)d_in[15];
  const float* e1b_bhh = (const float*)d_in[16];
  const float* d0_Wih  = (const float*)d_in[17];
  const float* d0_Whh  = (const float*)d_in[18];
  const float* d0_bih  = (const float*)d_in[19];
  const float* d0_bhh  = (const float*)d_in[20];
  const float* d1_Wih  = (const float*)d_in[21];
  const float* d1_Whh  = (const float*)d_in[22];
  const float* d1_bih  = (const float*)d_in[23];
  const float* d1_bhh  = (const float*)d_in[24];
  const float* emb     = (const float*)d_in[25];
  const float* Wout    = (const float*)d_in[26];
  const float* bout    = (const float*)d_in[27];
  const float* Wh0     = (const float*)d_in[28];
  const float* bh0     = (const float*)d_in[29];

  float* ws = (float*)d_ws;
  size_t off = 0;
  auto alloc = [&](size_t n){ float* q = ws + off; off += n; return q; };
  float* giA = alloc((size_t)N_*3*HE_);   // 2,764,800
  float* giB = alloc((size_t)N_*3*HE_);
  float* x0  = alloc((size_t)N_*2*HE_);   // reused for packed weights after gi1 gemms
  float* enc = alloc((size_t)N_*HE_);
  float* hfA = alloc((size_t)B_*HE_);
  float* hfB = alloc((size_t)B_*HE_);
  float* hbA = alloc((size_t)B_*HE_);
  float* hbB = alloc((size_t)B_*HE_);
  // decoder h-init buffers alias giA (dead after encoder)
  float* h0A = giA;
  float* h1A = giA + (size_t)N_*HD_;
  // packed decoder weights alias x0 (dead after gi1 gemms): 662,528 floats
  float4* Wih0P = (float4*)x0;                 // 13 x 768
  float4* Whh0P = Wih0P + (size_t)13*768;      // 64 x 768
  float4* Wih1P = Whh0P + (size_t)64*768;
  float4* Whh1P = Wih1P + (size_t)64*768;
  float4* WoP   = Whh1P + (size_t)64*768;      // 64 x 128
  float* Y = (float*)d_out;

  const dim3 blk(256);

  // ---- encoder layer 0 ----
  gemm_bias_kernel<0><<<dim3(15,48), blk, 0, stream>>>(wv, e0f_Wih, e0f_bih, giA, nullptr, N_, 3*HE_, D_);
  gemm_bias_kernel<0><<<dim3(15,48), blk, 0, stream>>>(wv, e0b_Wih, e0b_bih, giB, nullptr, N_, 3*HE_, D_);
  hipMemsetAsync(hfA, 0, (size_t)B_*HE_*sizeof(float), stream);
  hipMemsetAsync(hbA, 0, (size_t)B_*HE_*sizeof(float), stream);
  {
    float* hfi = hfA; float* hfo = hfB; float* hbi = hbA; float* hbo = hbB;
    for (int t = 0; t < S_; ++t) {
      enc_step_kernel<<<dim3(19,4,2), blk, 0, stream>>>(giA, giB, e0f_Whh, e0b_Whh,
          e0f_bhh, e0b_bhh, hfi, hfo, hbi, hbo, x0, t, 0);
      float* tmp = hfi; hfi = hfo; hfo = tmp;
      tmp = hbi; hbi = hbo; hbo = tmp;
    }
  }
  // ---- encoder layer 1 gi GEMMs (read x0) ----
  gemm_bias_kernel<0><<<dim3(15,48), blk, 0, stream>>>(x0, e1f_Wih, e1f_bih, giA, nullptr, N_, 3*HE_, 2*HE_);
  gemm_bias_kernel<0><<<dim3(15,48), blk, 0, stream>>>(x0, e1b_Wih, e1b_bih, giB, nullptr, N_, 3*HE_, 2*HE_);
  // ---- pack decoder weights (x0 region now dead) ----
  pack4_kernel<<<dim3(39),  blk, 0, stream>>>(d0_Wih, Wih0P, 3*HD_, E_,  13);
  pack4_kernel<<<dim3(192), blk, 0, stream>>>(d0_Whh, Whh0P, 3*HD_, HD_, 64);
  pack4_kernel<<<dim3(192), blk, 0, stream>>>(d1_Wih, Wih1P, 3*HD_, HD_, 64);
  pack4_kernel<<<dim3(192), blk, 0, stream>>>(d1_Whh, Whh1P, 3*HD_, HD_, 64);
  pack4_kernel<<<dim3(32),  blk, 0, stream>>>(Wout,   WoP,   A_,    HD_, 64);
  // ---- encoder layer 1 recurrence ----
  hipMemsetAsync(hfA, 0, (size_t)B_*HE_*sizeof(float), stream);
  hipMemsetAsync(hbA, 0, (size_t)B_*HE_*sizeof(float), stream);
  hipMemsetAsync(enc, 0, (size_t)N_*HE_*sizeof(float), stream);
  {
    float* hfi = hfA; float* hfo = hfB; float* hbi = hbA; float* hbo = hbB;
    for (int t = 0; t < S_; ++t) {
      enc_step_kernel<<<dim3(19,4,2), blk, 0, stream>>>(giA, giB, e1f_Whh, e1b_Whh,
          e1f_bhh, e1b_bhh, hfi, hfo, hbi, hbo, enc, t, 1);
      float* tmp = hfi; hfi = hfo; hfo = tmp;
      tmp = hbi; hbi = hbo; hbo = tmp;
    }
  }
  // ---- decoder init: h = tanh(enc@Wh0^T + bh0) -> h0A, h1A ----
  gemm_bias_kernel<1><<<dim3(8,48), blk, 0, stream>>>(enc, Wh0, bh0, h0A, h1A, N_, 2*HD_, HE_);
  // ---- persistent decoder: one launch, zero cross-block sync ----
  dec_persistent<<<dim3(N_/12), dim3(1024), 0, stream>>>(
      Wih0P, Whh0P, Wih1P, Whh1P, WoP,
      d0_bih, d0_bhh, d1_bih, d1_bhh, bout,
      emb, h0A, h1A, Y);
}

// Round 5
// 7835.458 us; speedup vs baseline: 1.9692x; 1.9692x over previous
//
#include <hip/hip_runtime.h>
#include <math.h>

#define S_ 48
#define B_ 64
#define D_ 300
#define HE_ 300
#define HD_ 256
#define E_ 50
#define A_ 128
#define T_ 50
#define N_ (S_*B_)   // 3072

__device__ __forceinline__ float sigm(float x){ return 1.0f/(1.0f + expf(-x)); }

// ---------------------------------------------------------------------------
// Generic GEMM: C(M,N) = A(M,K) @ W(N,K)^T + bias(N)
// MODE 0: store C row-major (A2 unused)
// MODE 2: A-tile = A + A2 elementwise; v = tanh(acc+bias);
//         cols [0,256) -> C[m*256+n], [256,512) -> C2
// ---------------------------------------------------------------------------
template<int MODE>
__global__ __launch_bounds__(256)
void gemm_bias_kernel(const float* __restrict__ A, const float* __restrict__ A2,
                      const float* __restrict__ W,
                      const float* __restrict__ bias, float* __restrict__ C,
                      float* __restrict__ C2, int M, int N, int K)
{
  __shared__ float As[16][64];
  __shared__ float Ws[16][64];
  const int tid = threadIdx.x;
  const int bm = blockIdx.y * 64;
  const int bn = blockIdx.x * 64;
  const int tx = tid & 15, ty = tid >> 4;
  const int lr = tid >> 2;
  const int lk = (tid & 3) << 2;
  float acc[4][4] = {{0.f}};
  for (int kb = 0; kb < K; kb += 16) {
    {
      const int row = bm + lr;
      const int k = kb + lk;
      const float* ap = A + (size_t)row * K + k;
      float4 v = make_float4(0.f,0.f,0.f,0.f);
      if (k + 3 < K) v = *reinterpret_cast<const float4*>(ap);
      else {
        if (k   < K) v.x = ap[0];
        if (k+1 < K) v.y = ap[1];
        if (k+2 < K) v.z = ap[2];
        if (k+3 < K) v.w = ap[3];
      }
      if (MODE == 2) {
        const float* ap2 = A2 + (size_t)row * K + k;
        if (k + 3 < K) {
          float4 v2 = *reinterpret_cast<const float4*>(ap2);
          v.x += v2.x; v.y += v2.y; v.z += v2.z; v.w += v2.w;
        } else {
          if (k   < K) v.x += ap2[0];
          if (k+1 < K) v.y += ap2[1];
          if (k+2 < K) v.z += ap2[2];
          if (k+3 < K) v.w += ap2[3];
        }
      }
      As[lk][lr]=v.x; As[lk+1][lr]=v.y; As[lk+2][lr]=v.z; As[lk+3][lr]=v.w;
    }
    {
      const int col = bn + lr;
      const int k = kb + lk;
      float4 v = make_float4(0.f,0.f,0.f,0.f);
      if (col < N) {
        const float* wp = W + (size_t)col * K + k;
        if (k + 3 < K) v = *reinterpret_cast<const float4*>(wp);
        else {
          if (k   < K) v.x = wp[0];
          if (k+1 < K) v.y = wp[1];
          if (k+2 < K) v.z = wp[2];
          if (k+3 < K) v.w = wp[3];
        }
      }
      Ws[lk][lr]=v.x; Ws[lk+1][lr]=v.y; Ws[lk+2][lr]=v.z; Ws[lk+3][lr]=v.w;
    }
    __syncthreads();
    #pragma unroll
    for (int kk = 0; kk < 16; ++kk) {
      float4 a4 = *reinterpret_cast<const float4*>(&As[kk][ty<<2]);
      float4 w4 = *reinterpret_cast<const float4*>(&Ws[kk][tx<<2]);
      const float* a = reinterpret_cast<const float*>(&a4);
      const float* w = reinterpret_cast<const float*>(&w4);
      #pragma unroll
      for (int i = 0; i < 4; ++i)
        #pragma unroll
        for (int j = 0; j < 4; ++j)
          acc[i][j] = fmaf(a[i], w[j], acc[i][j]);
    }
    __syncthreads();
  }
  #pragma unroll
  for (int i = 0; i < 4; ++i) {
    const int m = bm + (ty<<2) + i;
    #pragma unroll
    for (int j = 0; j < 4; ++j) {
      const int n = bn + (tx<<2) + j;
      if (n < N) {
        float v = acc[i][j] + bias[n];
        if (MODE == 0) {
          C[(size_t)m*N + n] = v;
        } else {
          v = tanhf(v);
          if (n < HD_) C[(size_t)m*HD_ + n] = v;
          else         C2[(size_t)m*HD_ + (n-HD_)] = v;
        }
      }
    }
  }
}

// ---------------------------------------------------------------------------
// Transpose with k-padding: in (NC, NK) row-major -> out (NKP, NC); rows
// k in [NK, NKP) are zero.
// ---------------------------------------------------------------------------
__global__ __launch_bounds__(256)
void transpose_kernel(const float* __restrict__ in, float* __restrict__ out,
                      int NC, int NK, int NKP)
{
  int idx = blockIdx.x * 256 + threadIdx.x;
  if (idx < NC*NKP) {
    int cI = idx / NKP, kI = idx % NKP;
    out[(size_t)kI*NC + cI] = (kI < NK) ? in[(size_t)cI*NK + kI] : 0.0f;
  }
}

// ---------------------------------------------------------------------------
// Persistent encoder layer: grid (8 row-groups, 2 dirs), 640 threads.
// Block owns 8 batch rows; all 48 steps inside, one barrier per step.
// Thread: half = tid/320 (4 rows each), j = tid%320 (gate-col, active <300).
// WhhT is k-major [300][900]. gi (incl. bih) precomputed.
// LAYER 0: out = x0 (S,B,600), dir halves. LAYER 1: dir 0 -> out, dir 1 -> outB.
// ---------------------------------------------------------------------------
template<int LAYER>
__global__ __launch_bounds__(640)
void enc_layer_persistent(const float* __restrict__ gi_f, const float* __restrict__ gi_b,
                          const float* __restrict__ WhhT_f, const float* __restrict__ WhhT_b,
                          const float* __restrict__ bhh_f, const float* __restrict__ bhh_b,
                          float* __restrict__ out, float* __restrict__ outB)
{
  const int dir = blockIdx.y;
  const float* gi  = dir ? gi_b   : gi_f;
  const float* WT  = dir ? WhhT_b : WhhT_f;
  const float* bhh = dir ? bhh_b  : bhh_f;
  float* o = (LAYER == 1 && dir) ? outB : out;

  __shared__ float hA[8][304];
  __shared__ float hB[8][304];
  const int tid = threadIdx.x;
  const int half = tid / 320;
  const int j = tid - half*320;
  const int R0 = blockIdx.x * 8;
  const int r0 = half * 4;
  const bool act = (j < HE_);

  float b_r = 0.f, b_z = 0.f, b_n = 0.f;
  if (act) { b_r = bhh[j]; b_z = bhh[HE_+j]; b_n = bhh[2*HE_+j]; }
  __syncthreads();

  for (int t = 0; t < S_; ++t) {
    const int tt = dir ? (S_-1 - t) : t;
    float (*hin)[304]  = (t & 1) ? hB : hA;
    float (*hout)[304] = (t & 1) ? hA : hB;
    float ar[4]={0,0,0,0}, az[4]={0,0,0,0}, an[4]={0,0,0,0};
    if (act && t > 0) {
      for (int k = 0; k < HE_; k += 4) {
        float wr[4], wz[4], wn[4];
        #pragma unroll
        for (int u = 0; u < 4; ++u) {
          const float* wk = WT + (size_t)(k+u)*(3*HE_);
          wr[u] = wk[j]; wz[u] = wk[HE_+j]; wn[u] = wk[2*HE_+j];
        }
        #pragma unroll
        for (int r = 0; r < 4; ++r) {
          float4 h4 = *reinterpret_cast<const float4*>(&hin[r0+r][k]);
          ar[r]=fmaf(h4.x,wr[0],ar[r]); ar[r]=fmaf(h4.y,wr[1],ar[r]);
          ar[r]=fmaf(h4.z,wr[2],ar[r]); ar[r]=fmaf(h4.w,wr[3],ar[r]);
          az[r]=fmaf(h4.x,wz[0],az[r]); az[r]=fmaf(h4.y,wz[1],az[r]);
          az[r]=fmaf(h4.z,wz[2],az[r]); az[r]=fmaf(h4.w,wz[3],az[r]);
          an[r]=fmaf(h4.x,wn[0],an[r]); an[r]=fmaf(h4.y,wn[1],an[r]);
          an[r]=fmaf(h4.z,wn[2],an[r]); an[r]=fmaf(h4.w,wn[3],an[r]);
        }
      }
    }
    if (act) {
      #pragma unroll
      for (int r = 0; r < 4; ++r) {
        const int row = R0 + r0 + r;
        const size_t gb = (size_t)(tt*B_ + row) * (3*HE_);
        float gr = gi[gb + j];
        float gz = gi[gb + HE_ + j];
        float gn = gi[gb + 2*HE_ + j];
        float rg = sigm(gr + ar[r] + b_r);
        float zg = sigm(gz + az[r] + b_z);
        float ng = tanhf(gn + rg*(an[r] + b_n));
        float ho = (t > 0) ? hin[r0+r][j] : 0.0f;
        float hn = (1.0f - zg)*ng + zg*ho;
        hout[r0+r][j] = hn;
        if (LAYER == 0) o[(size_t)(tt*B_ + row)*(2*HE_) + dir*HE_ + j] = hn;
        else            o[(size_t)(tt*B_ + row)*HE_ + j] = hn;
      }
    }
    __syncthreads();
  }
}

// ---------------------------------------------------------------------------
// Persistent decoder, zero cross-block deps. 256 blocks x 512 threads.
// Block owns 12 rows; h0/h1/es in LDS; scalar k-major weights from L2
// (round-3-proven access pattern). Merged K-loops: per k-quad, cell1 runs
// ih(h0) and hh(h1) together (24 indep FMA chains) to hide L2 latency.
// Thread: c = tid&255 (hidden col), half = tid>>8 -> rows half*6..+5.
// ---------------------------------------------------------------------------
__global__ __launch_bounds__(512)
void dec_persistent(const float* __restrict__ WihT0,  // [52][768] (rows 50,51 zero)
                    const float* __restrict__ WhhT0,  // [256][768]
                    const float* __restrict__ WihT1,  // [256][768]
                    const float* __restrict__ WhhT1,  // [256][768]
                    const float* __restrict__ WoutT,  // [256][128]
                    const float* __restrict__ bih0, const float* __restrict__ bhh0,
                    const float* __restrict__ bih1, const float* __restrict__ bhh1,
                    const float* __restrict__ bout,
                    const float* __restrict__ emb,
                    const float* __restrict__ h0init, const float* __restrict__ h1init,
                    float* __restrict__ Y)
{
  __shared__ float h0s[12][256];
  __shared__ float h1s[12][256];
  __shared__ float es[12][52];
  const int tid = threadIdx.x;
  const int R0 = blockIdx.x * 12;
  const int c  = tid & 255;
  const int half = tid >> 8;
  const int r0 = half * 6;

  for (int i = tid; i < 12*64; i += 512) {
    int r = i >> 6, k = (i & 63) << 2;
    *reinterpret_cast<float4*>(&h0s[r][k]) =
        *reinterpret_cast<const float4*>(&h0init[(size_t)(R0+r)*HD_ + k]);
    *reinterpret_cast<float4*>(&h1s[r][k]) =
        *reinterpret_cast<const float4*>(&h1init[(size_t)(R0+r)*HD_ + k]);
  }
  for (int i = tid; i < 12*52; i += 512) {
    int r = i / 52, k = i - r*52;
    es[r][k] = (k < E_) ? emb[E_ + k] : 0.0f;   // emb[SOS=1], zero pad
  }
  const float b0r = bih0[c] + bhh0[c];
  const float b0z = bih0[HD_+c] + bhh0[HD_+c];
  const float b0ni = bih0[2*HD_+c];
  const float b0nh = bhh0[2*HD_+c];
  const float b1r = bih1[c] + bhh1[c];
  const float b1z = bih1[HD_+c] + bhh1[HD_+c];
  const float b1ni = bih1[2*HD_+c];
  const float b1nh = bhh1[2*HD_+c];
  const float bo0 = bout[tid & 63];
  const float bo1 = bout[64 + (tid & 63)];
  __syncthreads();

  for (int s = 0; s < T_-1; ++s) {
    // ===== cell 0 (merged): hh over h0s (K=256) + ih over es (K=52) =======
    float ar[6]={0,0,0,0,0,0}, az[6]={0,0,0,0,0,0};
    float ani[6]={0,0,0,0,0,0}, anh[6]={0,0,0,0,0,0};
    for (int kq = 0; kq < 64; ++kq) {
      const int k = kq << 2;
      float wr[4], wz[4], wn[4];
      #pragma unroll
      for (int u = 0; u < 4; ++u) {
        const float* wk = WhhT0 + (size_t)(k+u)*768;
        wr[u]=wk[c]; wz[u]=wk[256+c]; wn[u]=wk[512+c];
      }
      #pragma unroll
      for (int r = 0; r < 6; ++r) {
        float4 x = *reinterpret_cast<const float4*>(&h0s[r0+r][k]);
        ar[r]=fmaf(x.x,wr[0],ar[r]); ar[r]=fmaf(x.y,wr[1],ar[r]);
        ar[r]=fmaf(x.z,wr[2],ar[r]); ar[r]=fmaf(x.w,wr[3],ar[r]);
        az[r]=fmaf(x.x,wz[0],az[r]); az[r]=fmaf(x.y,wz[1],az[r]);
        az[r]=fmaf(x.z,wz[2],az[r]); az[r]=fmaf(x.w,wz[3],az[r]);
        anh[r]=fmaf(x.x,wn[0],anh[r]); anh[r]=fmaf(x.y,wn[1],anh[r]);
        anh[r]=fmaf(x.z,wn[2],anh[r]); anh[r]=fmaf(x.w,wn[3],anh[r]);
      }
      if (kq < 13) {
        float vr[4], vz[4], vn[4];
        #pragma unroll
        for (int u = 0; u < 4; ++u) {
          const float* wk = WihT0 + (size_t)(k+u)*768;
          vr[u]=wk[c]; vz[u]=wk[256+c]; vn[u]=wk[512+c];
        }
        #pragma unroll
        for (int r = 0; r < 6; ++r) {
          float4 e = *reinterpret_cast<const float4*>(&es[r0+r][k]);
          ar[r]=fmaf(e.x,vr[0],ar[r]); ar[r]=fmaf(e.y,vr[1],ar[r]);
          ar[r]=fmaf(e.z,vr[2],ar[r]); ar[r]=fmaf(e.w,vr[3],ar[r]);
          az[r]=fmaf(e.x,vz[0],az[r]); az[r]=fmaf(e.y,vz[1],az[r]);
          az[r]=fmaf(e.z,vz[2],az[r]); az[r]=fmaf(e.w,vz[3],az[r]);
          ani[r]=fmaf(e.x,vn[0],ani[r]); ani[r]=fmaf(e.y,vn[1],ani[r]);
          ani[r]=fmaf(e.z,vn[2],ani[r]); ani[r]=fmaf(e.w,vn[3],ani[r]);
        }
      }
    }
    __syncthreads();
    {
      float hnew[6];
      #pragma unroll
      for (int r = 0; r < 6; ++r) {
        float rg = sigm(ar[r] + b0r);
        float zg = sigm(az[r] + b0z);
        float ng = tanhf(ani[r] + b0ni + rg*(anh[r] + b0nh));
        float hold = h0s[r0+r][c];
        hnew[r] = (1.0f - zg)*ng + zg*hold;
      }
      #pragma unroll
      for (int r = 0; r < 6; ++r) h0s[r0+r][c] = hnew[r];
    }
    __syncthreads();
    // ===== cell 1 (merged): ih over h0s + hh over h1s, both K=256 =========
    #pragma unroll
    for (int r = 0; r < 6; ++r) { ar[r]=0.f; az[r]=0.f; ani[r]=0.f; anh[r]=0.f; }
    for (int kq = 0; kq < 64; ++kq) {
      const int k = kq << 2;
      float vr[4], vz[4], vn[4], wr[4], wz[4], wn[4];
      #pragma unroll
      for (int u = 0; u < 4; ++u) {
        const float* wk  = WihT1 + (size_t)(k+u)*768;
        vr[u]=wk[c]; vz[u]=wk[256+c]; vn[u]=wk[512+c];
        const float* wk2 = WhhT1 + (size_t)(k+u)*768;
        wr[u]=wk2[c]; wz[u]=wk2[256+c]; wn[u]=wk2[512+c];
      }
      #pragma unroll
      for (int r = 0; r < 6; ++r) {
        float4 x = *reinterpret_cast<const float4*>(&h0s[r0+r][k]);
        ar[r]=fmaf(x.x,vr[0],ar[r]); ar[r]=fmaf(x.y,vr[1],ar[r]);
        ar[r]=fmaf(x.z,vr[2],ar[r]); ar[r]=fmaf(x.w,vr[3],ar[r]);
        az[r]=fmaf(x.x,vz[0],az[r]); az[r]=fmaf(x.y,vz[1],az[r]);
        az[r]=fmaf(x.z,vz[2],az[r]); az[r]=fmaf(x.w,vz[3],az[r]);
        ani[r]=fmaf(x.x,vn[0],ani[r]); ani[r]=fmaf(x.y,vn[1],ani[r]);
        ani[r]=fmaf(x.z,vn[2],ani[r]); ani[r]=fmaf(x.w,vn[3],ani[r]);
        float4 y = *reinterpret_cast<const float4*>(&h1s[r0+r][k]);
        ar[r]=fmaf(y.x,wr[0],ar[r]); ar[r]=fmaf(y.y,wr[1],ar[r]);
        ar[r]=fmaf(y.z,wr[2],ar[r]); ar[r]=fmaf(y.w,wr[3],ar[r]);
        az[r]=fmaf(y.x,wz[0],az[r]); az[r]=fmaf(y.y,wz[1],az[r]);
        az[r]=fmaf(y.z,wz[2],az[r]); az[r]=fmaf(y.w,wz[3],az[r]);
        anh[r]=fmaf(y.x,wn[0],anh[r]); anh[r]=fmaf(y.y,wn[1],anh[r]);
        anh[r]=fmaf(y.z,wn[2],anh[r]); anh[r]=fmaf(y.w,wn[3],anh[r]);
      }
    }
    __syncthreads();
    {
      float hnew[6];
      #pragma unroll
      for (int r = 0; r < 6; ++r) {
        float rg = sigm(ar[r] + b1r);
        float zg = sigm(az[r] + b1z);
        float ng = tanhf(ani[r] + b1ni + rg*(anh[r] + b1nh));
        float hold = h1s[r0+r][c];
        hnew[r] = (1.0f - zg)*ng + zg*hold;
      }
      #pragma unroll
      for (int r = 0; r < 6; ++r) h1s[r0+r][c] = hnew[r];
    }
    __syncthreads();
    // ===== logits + log_softmax + argmax + emb feedback ====================
    {
      const int w = tid >> 6;
      const int lane = tid & 63;
      if (w < 6) {
        const int row0 = 2*w;
        float a00=0.f, a01=0.f, a10=0.f, a11=0.f;
        for (int k = 0; k < HD_; k += 2) {
          float w00 = WoutT[(size_t)k*A_ + lane];
          float w01 = WoutT[(size_t)k*A_ + 64 + lane];
          float w10 = WoutT[(size_t)(k+1)*A_ + lane];
          float w11 = WoutT[(size_t)(k+1)*A_ + 64 + lane];
          float2 hv0 = *reinterpret_cast<const float2*>(&h1s[row0][k]);
          float2 hv1 = *reinterpret_cast<const float2*>(&h1s[row0+1][k]);
          a00 = fmaf(hv0.x, w00, a00); a00 = fmaf(hv0.y, w10, a00);
          a01 = fmaf(hv0.x, w01, a01); a01 = fmaf(hv0.y, w11, a01);
          a10 = fmaf(hv1.x, w00, a10); a10 = fmaf(hv1.y, w10, a10);
          a11 = fmaf(hv1.x, w01, a11); a11 = fmaf(hv1.y, w11, a11);
        }
        float va[2][2] = {{a00,a01},{a10,a11}};
        #pragma unroll
        for (int rr = 0; rr < 2; ++rr) {
          const int row = row0 + rr;
          float v0 = va[rr][0] + bo0;
          float v1 = va[rr][1] + bo1;
          float mx = fmaxf(v0, v1);
          #pragma unroll
          for (int off = 32; off >= 1; off >>= 1) mx = fmaxf(mx, __shfl_xor(mx, off));
          float sum = expf(v0 - mx) + expf(v1 - mx);
          #pragma unroll
          for (int off = 32; off >= 1; off >>= 1) sum += __shfl_xor(sum, off);
          float lz = mx + logf(sum);
          float* Yr = Y + ((size_t)s*N_ + R0 + row)*A_;
          Yr[lane]      = v0 - lz;
          Yr[64 + lane] = v1 - lz;
          float bv; int bi;
          if (v0 >= v1) { bv = v0; bi = lane; } else { bv = v1; bi = 64 + lane; }
          #pragma unroll
          for (int off = 32; off >= 1; off >>= 1) {
            float ov = __shfl_xor(bv, off);
            int   oi = __shfl_xor(bi, off);
            if (ov > bv || (ov == bv && oi < bi)) { bv = ov; bi = oi; }
          }
          if (lane < E_) es[row][lane] = emb[(size_t)bi*E_ + lane];
        }
      }
    }
    __syncthreads();
  }
}

// ---------------------------------------------------------------------------
extern "C" void kernel_launch(void* const* d_in, const int* in_sizes, int n_in,
                              void* d_out, int out_size, void* d_ws, size_t ws_size,
                              hipStream_t stream)
{
  (void)in_sizes; (void)n_in; (void)out_size; (void)ws_size;
  const float* wv      = (const float*)d_in[0];
  const float* e0f_Wih = (const float*)d_in[1];
  const float* e0f_Whh = (const float*)d_in[2];
  const float* e0f_bih = (const float*)d_in[3];
  const float* e0f_bhh = (const float*)d_in[4];
  const float* e0b_Wih = (const float*)d_in[5];
  const float* e0b_Whh = (const float*)d_in[6];
  const float* e0b_bih = (const float*)d_in[7];
  const float* e0b_bhh = (const float*)d_in[8];
  const float* e1f_Wih = (const float*)d_in[9];
  const float* e1f_Whh = (const float*)d_in[10];
  const float* e1f_bih = (const float*)d_in[11];
  const float* e1f_bhh = (const float*)d_in[12];
  const float* e1b_Wih = (const float*)d_in[13];
  const float* e1b_Whh = (const float*)d_in[14];
  const float* e1b_bih = (const float*)d_in[15];
  const float* e1b_bhh = (const float*)d_in[16];
  const float* d0_Wih  = (const float*)d_in[17];
  const float* d0_Whh  = (const float*)d_in[18];
  const float* d0_bih  = (const float*)d_in[19];
  const float* d0_bhh  = (const float*)d_in[20];
  const float* d1_Wih  = (const float*)d_in[21];
  const float* d1_Whh  = (const float*)d_in[22];
  const float* d1_bih  = (const float*)d_in[23];
  const float* d1_bhh  = (const float*)d_in[24];
  const float* emb     = (const float*)d_in[25];
  const float* Wout    = (const float*)d_in[26];
  const float* bout    = (const float*)d_in[27];
  const float* Wh0     = (const float*)d_in[28];
  const float* bh0     = (const float*)d_in[29];

  float* ws = (float*)d_ws;
  float* giA  = ws;                                   // 2,764,800
  float* giB  = giA + (size_t)N_*3*HE_;               // 2,764,800
  float* x0   = giB + (size_t)N_*3*HE_;               // 1,843,200
  float* eWhT = x0  + (size_t)N_*2*HE_;               // 1,080,000 (4 x 270,000)
  float* eT0f = eWhT;
  float* eT0b = eT0f + (size_t)3*HE_*HE_;
  float* eT1f = eT0b + (size_t)3*HE_*HE_;
  float* eT1b = eT1f + (size_t)3*HE_*HE_;
  // aliases (stream-ordered reuse):
  float* encF = x0;                                   // after gi1 gemms, x0 dead
  float* encB = x0 + (size_t)N_*HE_;
  float* h0A  = giA;                                  // after L1, gi dead
  float* h1A  = giA + (size_t)N_*HD_;
  // decoder transposed weights reuse eWhT (dead after L1): 662,528 <= 1,080,000
  float* WihT0 = eWhT;                                // 52 x 768
  float* WhhT0 = WihT0 + (size_t)52*768;              // 256 x 768
  float* WihT1 = WhhT0 + (size_t)HD_*768;
  float* WhhT1 = WihT1 + (size_t)HD_*768;
  float* WoutT = WhhT1 + (size_t)HD_*768;             // 256 x 128
  float* Y = (float*)d_out;

  const dim3 blk(256);

  // ---- encoder weight transposes (into eWhT) ----
  transpose_kernel<<<dim3((3*HE_*HE_+255)/256), blk, 0, stream>>>(e0f_Whh, eT0f, 3*HE_, HE_, HE_);
  transpose_kernel<<<dim3((3*HE_*HE_+255)/256), blk, 0, stream>>>(e0b_Whh, eT0b, 3*HE_, HE_, HE_);
  transpose_kernel<<<dim3((3*HE_*HE_+255)/256), blk, 0, stream>>>(e1f_Whh, eT1f, 3*HE_, HE_, HE_);
  transpose_kernel<<<dim3((3*HE_*HE_+255)/256), blk, 0, stream>>>(e1b_Whh, eT1b, 3*HE_, HE_, HE_);
  // ---- encoder layer 0 ----
  gemm_bias_kernel<0><<<dim3(15,48), blk, 0, stream>>>(wv, nullptr, e0f_Wih, e0f_bih, giA, nullptr, N_, 3*HE_, D_);
  gemm_bias_kernel<0><<<dim3(15,48), blk, 0, stream>>>(wv, nullptr, e0b_Wih, e0b_bih, giB, nullptr, N_, 3*HE_, D_);
  enc_layer_persistent<0><<<dim3(8,2), dim3(640), 0, stream>>>(giA, giB, eT0f, eT0b, e0f_bhh, e0b_bhh, x0, nullptr);
  // ---- encoder layer 1 ----
  gemm_bias_kernel<0><<<dim3(15,48), blk, 0, stream>>>(x0, nullptr, e1f_Wih, e1f_bih, giA, nullptr, N_, 3*HE_, 2*HE_);
  gemm_bias_kernel<0><<<dim3(15,48), blk, 0, stream>>>(x0, nullptr, e1b_Wih, e1b_bih, giB, nullptr, N_, 3*HE_, 2*HE_);
  enc_layer_persistent<1><<<dim3(8,2), dim3(640), 0, stream>>>(giA, giB, eT1f, eT1b, e1f_bhh, e1b_bhh, encF, encB);
  // ---- decoder weight transposes (eWhT now dead) ----
  transpose_kernel<<<dim3((768*52+255)/256),   blk, 0, stream>>>(d0_Wih, WihT0, 3*HD_, E_,  52);
  transpose_kernel<<<dim3((768*256+255)/256),  blk, 0, stream>>>(d0_Whh, WhhT0, 3*HD_, HD_, HD_);
  transpose_kernel<<<dim3((768*256+255)/256),  blk, 0, stream>>>(d1_Wih, WihT1, 3*HD_, HD_, HD_);
  transpose_kernel<<<dim3((768*256+255)/256),  blk, 0, stream>>>(d1_Whh, WhhT1, 3*HD_, HD_, HD_);
  transpose_kernel<<<dim3((128*256+255)/256),  blk, 0, stream>>>(Wout,   WoutT, A_,    HD_, HD_);
  // ---- decoder init: h = tanh((encF+encB)@Wh0^T + bh0) -> h0A, h1A ----
  gemm_bias_kernel<2><<<dim3(8,48), blk, 0, stream>>>(encF, encB, Wh0, bh0, h0A, h1A, N_, 2*HD_, HE_);
  // ---- persistent decoder ----
  dec_persistent<<<dim3(N_/12), dim3(512), 0, stream>>>(
      WihT0, WhhT0, WihT1, WhhT1, WoutT,
      d0_bih, d0_bhh, d1_bih, d1_bhh, bout,
      emb, h0A, h1A, Y);
}